// Round 11
// baseline (307.787 us; speedup 1.0000x reference)
//
#include <hip/hip_runtime.h>
#include <hip/hip_bf16.h>
#include <cstdint>
#include <cstddef>

#define NB 64      // batch
#define DD 256     // model dim
#define NN 625     // tokens = 25*25
#define NP 640     // padded token rows
#define NH 8       // heads
#define DH 32      // head dim
#define N3 768     // 3*DD
#define BSTR 640   // padded biasT stride
#define LDK 72     // GEMM LDS row pad (elements)
#define KVB 64     // attn j-tile
#define VSTR 72    // attn Vt row stride (144 B: conflict-free b128)

typedef __attribute__((ext_vector_type(8))) short bf16x8;
typedef __attribute__((ext_vector_type(4))) float f32x4;
typedef unsigned long long ull;

__device__ __forceinline__ unsigned short f2bf(float f) {
    unsigned int x = __builtin_bit_cast(unsigned int, f);
    return (unsigned short)((x + 0x7fffu + ((x >> 16) & 1u)) >> 16);   // RNE
}

// ---------------------------------------------------------------------------
// Generic transpose-cast: src (R x C) fp32 -> dst (C x R) bf16.  R,C % 64 == 0.
// ---------------------------------------------------------------------------
__global__ __launch_bounds__(256)
void transpose_cast(const float* __restrict__ src, unsigned short* __restrict__ dst,
                    int R, int C)
{
    __shared__ float T[64][65];
    const int c0 = blockIdx.x * 64, r0 = blockIdx.y * 64;
    const int tid = threadIdx.x;
    #pragma unroll
    for (int r = 0; r < 16; ++r) {
        const int flat = r * 256 + tid;
        const int rr = flat >> 6, cc = flat & 63;
        T[rr][cc] = src[(size_t)(r0 + rr) * C + c0 + cc];
    }
    __syncthreads();
    #pragma unroll
    for (int r = 0; r < 16; ++r) {
        const int flat = r * 256 + tid;
        const int cc = flat >> 6, rr = flat & 63;
        dst[(size_t)(c0 + cc) * R + r0 + rr] = f2bf(T[rr][cc]);
    }
}

// ---------------------------------------------------------------------------
// Bias gather into (h, j, i), 640x640 padded, pad = 0.  (R6-proven)
// ---------------------------------------------------------------------------
__global__ __launch_bounds__(256)
void biasT_kernel(const int* __restrict__ rel, const float* __restrict__ table,
                  float* __restrict__ biasT)
{
    __shared__ int sidx[64][65];
    const int i0 = blockIdx.x * 64, j0 = blockIdx.y * 64;
    const int tid = threadIdx.x;
    #pragma unroll
    for (int r = 0; r < 16; ++r) {
        const int flat = r * 256 + tid;
        const int ii = flat >> 6, jj = flat & 63;
        const int iG = i0 + ii, jG = j0 + jj;
        sidx[ii][jj] = (iG < NN && jG < NN) ? rel[(size_t)iG * NN + jG] : -1;
    }
    __syncthreads();
    for (int h = 0; h < NH; ++h) {
        #pragma unroll
        for (int r = 0; r < 16; ++r) {
            const int flat = r * 256 + tid;
            const int jj = flat >> 6, ii = flat & 63;
            const int iG = i0 + ii, jG = j0 + jj;
            const int idx = sidx[ii][jj];
            biasT[((size_t)h * BSTR + jG) * BSTR + iG] = (idx >= 0) ? table[idx * NH + h] : 0.f;
        }
    }
}

// ---------------------------------------------------------------------------
// QKV GEMM, m93-style, with x-transpose FUSED into A-staging (replaces the
// xT prepass: saves a full 122 MB HBM round-trip).  A tile As[i][k] staged
// straight from x (b, d, n): reads coalesced over i, transpose-cast writes
// (8-way bank alias on u16 writes, ~+60cyc/wave/ktile — cheaper than the
// prepass).  GEMM core / B staging / scatter epilogue unchanged from R5/R6.
// ---------------------------------------------------------------------------
__global__ __launch_bounds__(256)
void qkv_mfma(const float* __restrict__ x, const unsigned short* __restrict__ WT,
              unsigned short* __restrict__ Q, unsigned short* __restrict__ K,
              unsigned short* __restrict__ V)
{
    __shared__ unsigned short As[128][LDK];
    __shared__ unsigned short Bs[128][LDK];

    const int b = blockIdx.z, i0 = blockIdx.x * 128, j0 = blockIdx.y * 128;
    const int tid = threadIdx.x, lane = tid & 63, w = tid >> 6;
    const int lo = lane & 15, hi = lane >> 4;
    const int wr = w >> 1, wc = w & 1;

    // A staging: ii = tid&127 (two waves of consecutive i -> coalesced),
    // ks = tid>>7 selects k-slab of 32.
    const int aii = tid & 127;
    const int aks = (tid >> 7) * 32;
    const int gi  = i0 + aii;
    const bool iv = (gi < NN);
    const float* xcol = x + (size_t)b * DD * NN + (iv ? gi : 0);

    // B staging (unchanged): row = tid>>3, col8 = (tid&7)*8
    const int srow = tid >> 3;
    const int sc   = (tid & 7) * 8;

    f32x4 acc[4][4];
    #pragma unroll
    for (int a = 0; a < 4; ++a)
        #pragma unroll
        for (int t = 0; t < 4; ++t) acc[a][t] = (f32x4){0.f, 0.f, 0.f, 0.f};

    for (int k0 = 0; k0 < DD; k0 += 64) {
        // A: transpose-cast from x[b][k0+kk][gi]
        #pragma unroll
        for (int m = 0; m < 32; ++m) {
            const int kk = aks + m;
            const float v = iv ? xcol[(size_t)(k0 + kk) * NN] : 0.f;
            As[aii][kk] = f2bf(v);
        }
        // B: vector loads from WT (bf16, row-major K)
        #pragma unroll
        for (int p = 0; p < 4; ++p) {
            const int row = p * 32 + srow;
            *(bf16x8*)&Bs[row][sc] = *(const bf16x8*)&WT[(size_t)(j0 + row) * DD + k0 + sc];
        }
        __syncthreads();
        #pragma unroll
        for (int kk = 0; kk < 64; kk += 32) {
            bf16x8 af[4], bfr[4];
            #pragma unroll
            for (int a = 0; a < 4; ++a)
                af[a] = *(const bf16x8*)&As[wr * 64 + a * 16 + lo][kk + 8 * hi];
            #pragma unroll
            for (int t = 0; t < 4; ++t)
                bfr[t] = *(const bf16x8*)&Bs[wc * 64 + t * 16 + lo][kk + 8 * hi];
            #pragma unroll
            for (int a = 0; a < 4; ++a)
                #pragma unroll
                for (int t = 0; t < 4; ++t)
                    acc[a][t] = __builtin_amdgcn_mfma_f32_16x16x32_bf16(af[a], bfr[t], acc[a][t], 0, 0, 0);
        }
        __syncthreads();
    }

    #pragma unroll
    for (int t = 0; t < 4; ++t) {
        const int j  = j0 + wc * 64 + t * 16 + lo;
        const int tt = j >> 8;
        const int h  = (j & 255) >> 5;
        const int cb = j & 31;
        unsigned short* dst = (tt == 0) ? Q : (tt == 1) ? K : V;
        const float mul = (tt == 0) ? 0.17677669529663687f : 1.f;
        #pragma unroll
        for (int a = 0; a < 4; ++a) {
            #pragma unroll
            for (int r = 0; r < 4; ++r) {
                const int i = i0 + wr * 64 + a * 16 + 4 * hi + r;
                if (i < NN)
                    dst[(((size_t)b * NH + h) * NN + i) * DH + cb] = f2bf(acc[a][t][r] * mul);
            }
        }
    }
}

// ---------------------------------------------------------------------------
// MFMA flash attention — R6 version verbatim (proven: 137 us, absmax 1.22e-4).
// KVB=64 double-buffered K/V tiles, one barrier per tile, issue-early/
// write-late staging, bias register-prefetch; Pl LDS P-tile.
// ---------------------------------------------------------------------------
__global__ __launch_bounds__(256)
void attn_kernel(const unsigned short* __restrict__ Q,
                 const unsigned short* __restrict__ K,
                 const unsigned short* __restrict__ V,
                 const float* __restrict__ biasT, unsigned short* __restrict__ AO)
{
    __shared__ unsigned short Ks[2][KVB][40];    // [buf][j][k]   80 B rows
    __shared__ unsigned short Vt[2][DH][VSTR];   // [buf][d][j]  144 B rows
    __shared__ unsigned short Pl[4][16][40];     // per-wave P tile

    const int b  = blockIdx.z;
    const int h  = blockIdx.y;
    const int i0 = blockIdx.x * 64;
    const int tid  = threadIdx.x;
    const int lane = tid & 63;
    const int w    = tid >> 6;
    const int lo   = lane & 15;
    const int hi   = lane >> 4;

    const size_t hoff = ((size_t)b * NH + h) * (size_t)NN * DH;

    const int iq  = i0 + w * 16 + lo;
    const int iqc = (iq < NN) ? iq : (NN - 1);
    const bf16x8 qf = *(const bf16x8*)&Q[hoff + (size_t)iqc * DH + 8 * hi];

    const float* bh = biasT + (size_t)h * BSTR * BSTR;
    const int ibase = i0 + w * 16 + 4 * hi;

    // staging: row = tid&63 (lane-contiguous), d-slab = (tid>>6)*8 (wave-uniform)
    const int srow = tid & 63;
    const int sc   = (tid >> 6) * 8;

    f32x4 acc0 = {0.f, 0.f, 0.f, 0.f};
    f32x4 acc1 = {0.f, 0.f, 0.f, 0.f};
    float lsum[4] = {0.f, 0.f, 0.f, 0.f};

    // ---- prologue: tile 0 into buf 0, bias tile 0 into regs ----
    {
        bf16x8 k0 = {0,0,0,0,0,0,0,0}, v0 = {0,0,0,0,0,0,0,0};
        if (srow < NN) {
            k0 = *(const bf16x8*)&K[hoff + (size_t)srow * DH + sc];
            v0 = *(const bf16x8*)&V[hoff + (size_t)srow * DH + sc];
        }
        *(bf16x8*)&Ks[0][srow][sc] = k0;
        #pragma unroll
        for (int e = 0; e < 8; ++e) Vt[0][sc + e][srow] = (unsigned short)v0[e];
    }
    f32x4 bc[4];
    #pragma unroll
    for (int r = 0; r < 4; ++r)
        bc[r] = *(const f32x4*)&bh[(size_t)(r * 16 + lo) * BSTR + ibase];
    __syncthreads();

    for (int t = 0; t < 10; ++t) {
        const int cur = t & 1;
        // ---- issue next-tile global loads (consumed after compute) ----
        bf16x8 kn = {0,0,0,0,0,0,0,0}, vn = {0,0,0,0,0,0,0,0};
        f32x4 bn[4];
        const int jn = (t + 1) * KVB;
        if (t < 9) {
            const int jr = jn + srow;
            if (jr < NN) {
                kn = *(const bf16x8*)&K[hoff + (size_t)jr * DH + sc];
                vn = *(const bf16x8*)&V[hoff + (size_t)jr * DH + sc];
            }
            #pragma unroll
            for (int r = 0; r < 4; ++r)
                bn[r] = *(const f32x4*)&bh[(size_t)(jn + r * 16 + lo) * BSTR + ibase];
        }
        // ---- compute two 32-j substeps on buf[cur] ----
        #pragma unroll
        for (int s = 0; s < 2; ++s) {
            const int js = s * 32;
            const int jbase = t * KVB + js;
            const bf16x8 kf0 = *(const bf16x8*)&Ks[cur][js + lo][8 * hi];
            const bf16x8 kf1 = *(const bf16x8*)&Ks[cur][js + 16 + lo][8 * hi];
            const f32x4 s0 = __builtin_amdgcn_mfma_f32_16x16x32_bf16(qf, kf0, bc[2*s+0], 0, 0, 0);
            const f32x4 s1 = __builtin_amdgcn_mfma_f32_16x16x32_bf16(qf, kf1, bc[2*s+1], 0, 0, 0);
            const bool v0 = (jbase + lo) < NN;
            const bool v1 = (jbase + 16 + lo) < NN;
            float p0[4], p1[4];
            #pragma unroll
            for (int r = 0; r < 4; ++r) {
                p0[r] = v0 ? __expf(s0[r]) : 0.f;
                p1[r] = v1 ? __expf(s1[r]) : 0.f;
                lsum[r] += p0[r] + p1[r];
            }
            #pragma unroll
            for (int r = 0; r < 4; ++r) {
                Pl[w][4 * hi + r][lo]      = f2bf(p0[r]);
                Pl[w][4 * hi + r][16 + lo] = f2bf(p1[r]);
            }
            const bf16x8 pf  = *(const bf16x8*)&Pl[w][lo][8 * hi];
            const bf16x8 vf0 = *(const bf16x8*)&Vt[cur][lo][js + 8 * hi];
            const bf16x8 vf1 = *(const bf16x8*)&Vt[cur][16 + lo][js + 8 * hi];
            acc0 = __builtin_amdgcn_mfma_f32_16x16x32_bf16(pf, vf0, acc0, 0, 0, 0);
            acc1 = __builtin_amdgcn_mfma_f32_16x16x32_bf16(pf, vf1, acc1, 0, 0, 0);
        }
        // ---- write next tile into the other buffer, rotate bias regs ----
        if (t < 9) {
            *(bf16x8*)&Ks[cur ^ 1][srow][sc] = kn;
            #pragma unroll
            for (int e = 0; e < 8; ++e) Vt[cur ^ 1][sc + e][srow] = (unsigned short)vn[e];
            #pragma unroll
            for (int r = 0; r < 4; ++r) bc[r] = bn[r];
        }
        __syncthreads();
    }

    #pragma unroll
    for (int off = 1; off < 16; off <<= 1)
        #pragma unroll
        for (int r = 0; r < 4; ++r)
            lsum[r] += __shfl_xor(lsum[r], off, 64);

    #pragma unroll
    for (int r = 0; r < 4; ++r) {
        const int i = ibase + r;
        if (i < NN) {
            const float inv = 1.f / lsum[r];
            unsigned short* dst = AO + ((size_t)b * NP + i) * DD + h * DH;
            dst[lo]      = f2bf(acc0[r] * inv);
            dst[16 + lo] = f2bf(acc1[r] * inv);
        }
    }
}

// ---------------------------------------------------------------------------
// Output projection, m93-style (unchanged from R5/R6).
// ---------------------------------------------------------------------------
__global__ __launch_bounds__(256)
void outproj_mfma(const unsigned short* __restrict__ AO, const unsigned short* __restrict__ WoT,
                  float* __restrict__ out)
{
    __shared__ unsigned short As[128][LDK];
    __shared__ unsigned short Bs[128][LDK];

    const int b = blockIdx.z, i0 = blockIdx.x * 128, j0 = blockIdx.y * 128;
    const int tid = threadIdx.x, lane = tid & 63, w = tid >> 6;
    const int lo = lane & 15, hi = lane >> 4;
    const int wr = w >> 1, wc = w & 1;

    const unsigned short* Abase = AO + (size_t)b * NP * DD;

    const int srow = tid >> 3;
    const int sc   = (tid & 7) * 8;

    f32x4 acc[4][4];
    #pragma unroll
    for (int a = 0; a < 4; ++a)
        #pragma unroll
        for (int t = 0; t < 4; ++t) acc[a][t] = (f32x4){0.f, 0.f, 0.f, 0.f};

    for (int k0 = 0; k0 < DD; k0 += 64) {
        #pragma unroll
        for (int p = 0; p < 4; ++p) {
            const int row = p * 32 + srow;
            *(bf16x8*)&As[row][sc] = *(const bf16x8*)&Abase[(size_t)(i0 + row) * DD + k0 + sc];
            *(bf16x8*)&Bs[row][sc] = *(const bf16x8*)&WoT[(size_t)(j0 + row) * DD + k0 + sc];
        }
        __syncthreads();
        #pragma unroll
        for (int kk = 0; kk < 64; kk += 32) {
            bf16x8 af[4], bfr[4];
            #pragma unroll
            for (int a = 0; a < 4; ++a)
                af[a] = *(const bf16x8*)&As[wr * 64 + a * 16 + lo][kk + 8 * hi];
            #pragma unroll
            for (int t = 0; t < 4; ++t)
                bfr[t] = *(const bf16x8*)&Bs[wc * 64 + t * 16 + lo][kk + 8 * hi];
            #pragma unroll
            for (int a = 0; a < 4; ++a)
                #pragma unroll
                for (int t = 0; t < 4; ++t)
                    acc[a][t] = __builtin_amdgcn_mfma_f32_16x16x32_bf16(af[a], bfr[t], acc[a][t], 0, 0, 0);
        }
        __syncthreads();
    }

    #pragma unroll
    for (int t = 0; t < 4; ++t) {
        const int j = j0 + wc * 64 + t * 16 + lo;
        float* dst = out + ((size_t)b * DD + j) * NN;
        #pragma unroll
        for (int a = 0; a < 4; ++a) {
            #pragma unroll
            for (int r = 0; r < 4; ++r) {
                const int i = i0 + wr * 64 + a * 16 + 4 * hi + r;
                if (i < NN) dst[i] = acc[a][t][r];
            }
        }
    }
}

// ---------------------------------------------------------------------------
extern "C" void kernel_launch(void* const* d_in, const int* in_sizes, int n_in,
                              void* d_out, int out_size, void* d_ws, size_t ws_size,
                              hipStream_t stream)
{
    (void)in_sizes; (void)n_in; (void)out_size; (void)ws_size;
    const float* x     = (const float*)d_in[0];
    const float* w_qkv = (const float*)d_in[1];
    const float* w_out = (const float*)d_in[2];
    const float* table = (const float*)d_in[3];
    const int*   rel   = (const int*)d_in[4];
    float* out = (float*)d_out;

    unsigned short* ws16 = (unsigned short*)d_ws;
    const size_t szQ  = (size_t)NB * NH * NN * DH;   // 10,240,000
    const size_t szXT = (size_t)NB * NP * DD;        // 10,485,760
    unsigned short* Q   = ws16;
    unsigned short* K   = Q + szQ;
    unsigned short* V   = K + szQ;
    unsigned short* WT  = V + szQ;                   // 768*256
    unsigned short* WoT = WT + (size_t)N3 * DD;      // 256*256
    unsigned short* AO  = WoT + (size_t)DD * DD;     // (b, 640, 256) bf16
    float* BT = (float*)(AO + szXT);                 // (8, 640, 640) fp32, (h,j,i)

    transpose_cast<<<dim3(12, 4, 1),  256, 0, stream>>>(w_qkv, WT, DD, N3);
    transpose_cast<<<dim3(4, 4, 1),   256, 0, stream>>>(w_out, WoT, DD, DD);
    biasT_kernel  <<<dim3(10, 10, 1), 256, 0, stream>>>(rel, table, BT);
    qkv_mfma      <<<dim3(5, 6, NB),  256, 0, stream>>>(x, WT, Q, K, V);
    attn_kernel   <<<dim3(10, NH, NB), 256, 0, stream>>>(Q, K, V, BT, AO);
    outproj_mfma  <<<dim3(5, 2, NB),  256, 0, stream>>>(AO, WoT, out);
}

// Round 12
// 256.527 us; speedup vs baseline: 1.1998x; 1.1998x over previous
//
#include <hip/hip_runtime.h>
#include <hip/hip_bf16.h>
#include <cstdint>
#include <cstddef>

#define NB 64      // batch
#define DD 256     // model dim
#define NN 625     // tokens = 25*25
#define NP 640     // padded token rows
#define NH 8       // heads
#define DH 32      // head dim
#define N3 768     // 3*DD
#define BSTR 640   // padded biasT stride
#define LDK 72     // GEMM LDS row pad (elements)
#define KVB 64     // attn j-tile
#define VSTR 72    // attn Vt row stride (144 B: conflict-free b128)

typedef __attribute__((ext_vector_type(8))) short bf16x8;
typedef __attribute__((ext_vector_type(4))) float f32x4;
typedef unsigned int u32;
typedef unsigned long long ull;

__device__ __forceinline__ unsigned short f2bf(float f) {
    u32 x = __builtin_bit_cast(u32, f);
    return (unsigned short)((x + 0x7fffu + ((x >> 16) & 1u)) >> 16);   // RNE
}
__device__ __forceinline__ f32x4 bf4_to_f32(ushort4 v) {
    f32x4 r;
    r[0] = __builtin_bit_cast(float, (u32)v.x << 16);
    r[1] = __builtin_bit_cast(float, (u32)v.y << 16);
    r[2] = __builtin_bit_cast(float, (u32)v.z << 16);
    r[3] = __builtin_bit_cast(float, (u32)v.w << 16);
    return r;
}

// ---------------------------------------------------------------------------
// x (b, 256, 625) fp32  ->  XT (b, 640, 256) bf16  (transpose + cast; pad = 0)
// ---------------------------------------------------------------------------
__global__ __launch_bounds__(256)
void xT_kernel(const float* __restrict__ x, unsigned short* __restrict__ XT)
{
    __shared__ float T[64][65];
    const int b = blockIdx.z, n0 = blockIdx.x * 64, d0 = blockIdx.y * 64;
    const int tid = threadIdx.x;
    const float* xb = x + (size_t)b * DD * NN;
    #pragma unroll
    for (int r = 0; r < 16; ++r) {
        const int flat = r * 256 + tid;
        const int dd = flat >> 6, ii = flat & 63;      // ii fast: coalesced read
        const int n = n0 + ii;
        T[dd][ii] = (n < NN) ? xb[(size_t)(d0 + dd) * NN + n] : 0.f;
    }
    __syncthreads();
    #pragma unroll
    for (int r = 0; r < 16; ++r) {
        const int flat = r * 256 + tid;
        const int ii = flat >> 6, dd = flat & 63;      // dd fast: coalesced write
        XT[((size_t)b * NP + n0 + ii) * DD + d0 + dd] = f2bf(T[dd][ii]);
    }
}

// ---------------------------------------------------------------------------
// Generic transpose-cast: src (R x C) fp32 -> dst (C x R) bf16.  R,C % 64 == 0.
// ---------------------------------------------------------------------------
__global__ __launch_bounds__(256)
void transpose_cast(const float* __restrict__ src, unsigned short* __restrict__ dst,
                    int R, int C)
{
    __shared__ float T[64][65];
    const int c0 = blockIdx.x * 64, r0 = blockIdx.y * 64;
    const int tid = threadIdx.x;
    #pragma unroll
    for (int r = 0; r < 16; ++r) {
        const int flat = r * 256 + tid;
        const int rr = flat >> 6, cc = flat & 63;
        T[rr][cc] = src[(size_t)(r0 + rr) * C + c0 + cc];
    }
    __syncthreads();
    #pragma unroll
    for (int r = 0; r < 16; ++r) {
        const int flat = r * 256 + tid;
        const int cc = flat >> 6, rr = flat & 63;
        dst[(size_t)(c0 + cc) * R + r0 + rr] = f2bf(T[rr][cc]);
    }
}

// ---------------------------------------------------------------------------
// Bias gather into (h, j, i), 640x640 padded, pad = 0 — stored as BF16
// (halves write traffic here and bias fetch traffic in attn).
// ---------------------------------------------------------------------------
__global__ __launch_bounds__(256)
void biasT_kernel(const int* __restrict__ rel, const float* __restrict__ table,
                  unsigned short* __restrict__ biasT)
{
    __shared__ int sidx[64][65];
    const int i0 = blockIdx.x * 64, j0 = blockIdx.y * 64;
    const int tid = threadIdx.x;
    #pragma unroll
    for (int r = 0; r < 16; ++r) {
        const int flat = r * 256 + tid;
        const int ii = flat >> 6, jj = flat & 63;
        const int iG = i0 + ii, jG = j0 + jj;
        sidx[ii][jj] = (iG < NN && jG < NN) ? rel[(size_t)iG * NN + jG] : -1;
    }
    __syncthreads();
    for (int h = 0; h < NH; ++h) {
        #pragma unroll
        for (int r = 0; r < 16; ++r) {
            const int flat = r * 256 + tid;
            const int jj = flat >> 6, ii = flat & 63;
            const int iG = i0 + ii, jG = j0 + jj;
            const int idx = sidx[ii][jj];
            biasT[((size_t)h * BSTR + jG) * BSTR + iG] =
                (idx >= 0) ? f2bf(table[idx * NH + h]) : (unsigned short)0;
        }
    }
}

// ---------------------------------------------------------------------------
// QKV GEMM, m93-style (R5/R6-proven, reads XT prepass output).
// ---------------------------------------------------------------------------
__global__ __launch_bounds__(256)
void qkv_mfma(const unsigned short* __restrict__ XT, const unsigned short* __restrict__ WT,
              unsigned short* __restrict__ Q, unsigned short* __restrict__ K,
              unsigned short* __restrict__ V)
{
    __shared__ unsigned short As[128][LDK];
    __shared__ unsigned short Bs[128][LDK];

    const int b = blockIdx.z, i0 = blockIdx.x * 128, j0 = blockIdx.y * 128;
    const int tid = threadIdx.x, lane = tid & 63, w = tid >> 6;
    const int lo = lane & 15, hi = lane >> 4;
    const int wr = w >> 1, wc = w & 1;

    const unsigned short* Abase = XT + (size_t)b * NP * DD;
    const unsigned short* Bbase = WT;

    const int srow = tid >> 3;
    const int sc   = (tid & 7) * 8;

    f32x4 acc[4][4];
    #pragma unroll
    for (int a = 0; a < 4; ++a)
        #pragma unroll
        for (int t = 0; t < 4; ++t) acc[a][t] = (f32x4){0.f, 0.f, 0.f, 0.f};

    for (int k0 = 0; k0 < DD; k0 += 64) {
        #pragma unroll
        for (int p = 0; p < 4; ++p) {
            const int row = p * 32 + srow;
            *(bf16x8*)&As[row][sc] = *(const bf16x8*)&Abase[(size_t)(i0 + row) * DD + k0 + sc];
            *(bf16x8*)&Bs[row][sc] = *(const bf16x8*)&Bbase[(size_t)(j0 + row) * DD + k0 + sc];
        }
        __syncthreads();
        #pragma unroll
        for (int kk = 0; kk < 64; kk += 32) {
            bf16x8 af[4], bfr[4];
            #pragma unroll
            for (int a = 0; a < 4; ++a)
                af[a] = *(const bf16x8*)&As[wr * 64 + a * 16 + lo][kk + 8 * hi];
            #pragma unroll
            for (int t = 0; t < 4; ++t)
                bfr[t] = *(const bf16x8*)&Bs[wc * 64 + t * 16 + lo][kk + 8 * hi];
            #pragma unroll
            for (int a = 0; a < 4; ++a)
                #pragma unroll
                for (int t = 0; t < 4; ++t)
                    acc[a][t] = __builtin_amdgcn_mfma_f32_16x16x32_bf16(af[a], bfr[t], acc[a][t], 0, 0, 0);
        }
        __syncthreads();
    }

    #pragma unroll
    for (int t = 0; t < 4; ++t) {
        const int j  = j0 + wc * 64 + t * 16 + lo;
        const int tt = j >> 8;
        const int h  = (j & 255) >> 5;
        const int cb = j & 31;
        unsigned short* dst = (tt == 0) ? Q : (tt == 1) ? K : V;
        const float mul = (tt == 0) ? 0.17677669529663687f : 1.f;
        #pragma unroll
        for (int a = 0; a < 4; ++a) {
            #pragma unroll
            for (int r = 0; r < 4; ++r) {
                const int i = i0 + wr * 64 + a * 16 + 4 * hi + r;
                if (i < NN)
                    dst[(((size_t)b * NH + h) * NN + i) * DH + cb] = f2bf(acc[a][t][r] * mul);
            }
        }
    }
}

// ---------------------------------------------------------------------------
// MFMA flash attention — R6 structure verbatim (proven), ONE delta: bias is
// bf16 (ushort4 loads + shift-convert to the f32x4 C operand).
// ---------------------------------------------------------------------------
__global__ __launch_bounds__(256)
void attn_kernel(const unsigned short* __restrict__ Q,
                 const unsigned short* __restrict__ K,
                 const unsigned short* __restrict__ V,
                 const unsigned short* __restrict__ biasT, unsigned short* __restrict__ AO)
{
    __shared__ unsigned short Ks[2][KVB][40];    // [buf][j][k]   80 B rows
    __shared__ unsigned short Vt[2][DH][VSTR];   // [buf][d][j]  144 B rows
    __shared__ unsigned short Pl[4][16][40];     // per-wave P tile

    const int b  = blockIdx.z;
    const int h  = blockIdx.y;
    const int i0 = blockIdx.x * 64;
    const int tid  = threadIdx.x;
    const int lane = tid & 63;
    const int w    = tid >> 6;
    const int lo   = lane & 15;
    const int hi   = lane >> 4;

    const size_t hoff = ((size_t)b * NH + h) * (size_t)NN * DH;

    const int iq  = i0 + w * 16 + lo;
    const int iqc = (iq < NN) ? iq : (NN - 1);
    const bf16x8 qf = *(const bf16x8*)&Q[hoff + (size_t)iqc * DH + 8 * hi];

    const unsigned short* bh = biasT + (size_t)h * BSTR * BSTR;
    const int ibase = i0 + w * 16 + 4 * hi;

    // staging: row = tid&63 (lane-contiguous), d-slab = (tid>>6)*8 (wave-uniform)
    const int srow = tid & 63;
    const int sc   = (tid >> 6) * 8;

    f32x4 acc0 = {0.f, 0.f, 0.f, 0.f};
    f32x4 acc1 = {0.f, 0.f, 0.f, 0.f};
    float lsum[4] = {0.f, 0.f, 0.f, 0.f};

    // ---- prologue: tile 0 into buf 0, bias tile 0 into regs ----
    {
        bf16x8 k0 = {0,0,0,0,0,0,0,0}, v0 = {0,0,0,0,0,0,0,0};
        if (srow < NN) {
            k0 = *(const bf16x8*)&K[hoff + (size_t)srow * DH + sc];
            v0 = *(const bf16x8*)&V[hoff + (size_t)srow * DH + sc];
        }
        *(bf16x8*)&Ks[0][srow][sc] = k0;
        #pragma unroll
        for (int e = 0; e < 8; ++e) Vt[0][sc + e][srow] = (unsigned short)v0[e];
    }
    ushort4 bc[4];
    #pragma unroll
    for (int r = 0; r < 4; ++r)
        bc[r] = *(const ushort4*)&bh[(size_t)(r * 16 + lo) * BSTR + ibase];
    __syncthreads();

    for (int t = 0; t < 10; ++t) {
        const int cur = t & 1;
        // ---- issue next-tile global loads (consumed after compute) ----
        bf16x8 kn = {0,0,0,0,0,0,0,0}, vn = {0,0,0,0,0,0,0,0};
        ushort4 bn[4];
        const int jn = (t + 1) * KVB;
        if (t < 9) {
            const int jr = jn + srow;
            if (jr < NN) {
                kn = *(const bf16x8*)&K[hoff + (size_t)jr * DH + sc];
                vn = *(const bf16x8*)&V[hoff + (size_t)jr * DH + sc];
            }
            #pragma unroll
            for (int r = 0; r < 4; ++r)
                bn[r] = *(const ushort4*)&bh[(size_t)(jn + r * 16 + lo) * BSTR + ibase];
        }
        // ---- compute two 32-j substeps on buf[cur] ----
        #pragma unroll
        for (int s = 0; s < 2; ++s) {
            const int js = s * 32;
            const int jbase = t * KVB + js;
            const bf16x8 kf0 = *(const bf16x8*)&Ks[cur][js + lo][8 * hi];
            const bf16x8 kf1 = *(const bf16x8*)&Ks[cur][js + 16 + lo][8 * hi];
            const f32x4 s0 = __builtin_amdgcn_mfma_f32_16x16x32_bf16(qf, kf0, bf4_to_f32(bc[2*s+0]), 0, 0, 0);
            const f32x4 s1 = __builtin_amdgcn_mfma_f32_16x16x32_bf16(qf, kf1, bf4_to_f32(bc[2*s+1]), 0, 0, 0);
            const bool v0 = (jbase + lo) < NN;
            const bool v1 = (jbase + 16 + lo) < NN;
            float p0[4], p1[4];
            #pragma unroll
            for (int r = 0; r < 4; ++r) {
                p0[r] = v0 ? __expf(s0[r]) : 0.f;
                p1[r] = v1 ? __expf(s1[r]) : 0.f;
                lsum[r] += p0[r] + p1[r];
            }
            #pragma unroll
            for (int r = 0; r < 4; ++r) {
                Pl[w][4 * hi + r][lo]      = f2bf(p0[r]);
                Pl[w][4 * hi + r][16 + lo] = f2bf(p1[r]);
            }
            const bf16x8 pf  = *(const bf16x8*)&Pl[w][lo][8 * hi];
            const bf16x8 vf0 = *(const bf16x8*)&Vt[cur][lo][js + 8 * hi];
            const bf16x8 vf1 = *(const bf16x8*)&Vt[cur][16 + lo][js + 8 * hi];
            acc0 = __builtin_amdgcn_mfma_f32_16x16x32_bf16(pf, vf0, acc0, 0, 0, 0);
            acc1 = __builtin_amdgcn_mfma_f32_16x16x32_bf16(pf, vf1, acc1, 0, 0, 0);
        }
        // ---- write next tile into the other buffer, rotate bias regs ----
        if (t < 9) {
            *(bf16x8*)&Ks[cur ^ 1][srow][sc] = kn;
            #pragma unroll
            for (int e = 0; e < 8; ++e) Vt[cur ^ 1][sc + e][srow] = (unsigned short)vn[e];
            #pragma unroll
            for (int r = 0; r < 4; ++r) bc[r] = bn[r];
        }
        __syncthreads();
    }

    #pragma unroll
    for (int off = 1; off < 16; off <<= 1)
        #pragma unroll
        for (int r = 0; r < 4; ++r)
            lsum[r] += __shfl_xor(lsum[r], off, 64);

    #pragma unroll
    for (int r = 0; r < 4; ++r) {
        const int i = ibase + r;
        if (i < NN) {
            const float inv = 1.f / lsum[r];
            unsigned short* dst = AO + ((size_t)b * NP + i) * DD + h * DH;
            dst[lo]      = f2bf(acc0[r] * inv);
            dst[16 + lo] = f2bf(acc1[r] * inv);
        }
    }
}

// ---------------------------------------------------------------------------
// Output projection, m93-style (unchanged from R5/R6).
// ---------------------------------------------------------------------------
__global__ __launch_bounds__(256)
void outproj_mfma(const unsigned short* __restrict__ AO, const unsigned short* __restrict__ WoT,
                  float* __restrict__ out)
{
    __shared__ unsigned short As[128][LDK];
    __shared__ unsigned short Bs[128][LDK];

    const int b = blockIdx.z, i0 = blockIdx.x * 128, j0 = blockIdx.y * 128;
    const int tid = threadIdx.x, lane = tid & 63, w = tid >> 6;
    const int lo = lane & 15, hi = lane >> 4;
    const int wr = w >> 1, wc = w & 1;

    const unsigned short* Abase = AO + (size_t)b * NP * DD;

    const int srow = tid >> 3;
    const int sc   = (tid & 7) * 8;

    f32x4 acc[4][4];
    #pragma unroll
    for (int a = 0; a < 4; ++a)
        #pragma unroll
        for (int t = 0; t < 4; ++t) acc[a][t] = (f32x4){0.f, 0.f, 0.f, 0.f};

    for (int k0 = 0; k0 < DD; k0 += 64) {
        #pragma unroll
        for (int p = 0; p < 4; ++p) {
            const int row = p * 32 + srow;
            *(bf16x8*)&As[row][sc] = *(const bf16x8*)&Abase[(size_t)(i0 + row) * DD + k0 + sc];
            *(bf16x8*)&Bs[row][sc] = *(const bf16x8*)&WoT[(size_t)(j0 + row) * DD + k0 + sc];
        }
        __syncthreads();
        #pragma unroll
        for (int kk = 0; kk < 64; kk += 32) {
            bf16x8 af[4], bfr[4];
            #pragma unroll
            for (int a = 0; a < 4; ++a)
                af[a] = *(const bf16x8*)&As[wr * 64 + a * 16 + lo][kk + 8 * hi];
            #pragma unroll
            for (int t = 0; t < 4; ++t)
                bfr[t] = *(const bf16x8*)&Bs[wc * 64 + t * 16 + lo][kk + 8 * hi];
            #pragma unroll
            for (int a = 0; a < 4; ++a)
                #pragma unroll
                for (int t = 0; t < 4; ++t)
                    acc[a][t] = __builtin_amdgcn_mfma_f32_16x16x32_bf16(af[a], bfr[t], acc[a][t], 0, 0, 0);
        }
        __syncthreads();
    }

    #pragma unroll
    for (int t = 0; t < 4; ++t) {
        const int j = j0 + wc * 64 + t * 16 + lo;
        float* dst = out + ((size_t)b * DD + j) * NN;
        #pragma unroll
        for (int a = 0; a < 4; ++a) {
            #pragma unroll
            for (int r = 0; r < 4; ++r) {
                const int i = i0 + wr * 64 + a * 16 + 4 * hi + r;
                if (i < NN) dst[i] = acc[a][t][r];
            }
        }
    }
}

// ---------------------------------------------------------------------------
extern "C" void kernel_launch(void* const* d_in, const int* in_sizes, int n_in,
                              void* d_out, int out_size, void* d_ws, size_t ws_size,
                              hipStream_t stream)
{
    (void)in_sizes; (void)n_in; (void)out_size; (void)ws_size;
    const float* x     = (const float*)d_in[0];
    const float* w_qkv = (const float*)d_in[1];
    const float* w_out = (const float*)d_in[2];
    const float* table = (const float*)d_in[3];
    const int*   rel   = (const int*)d_in[4];
    float* out = (float*)d_out;

    unsigned short* ws16 = (unsigned short*)d_ws;
    const size_t szQ  = (size_t)NB * NH * NN * DH;   // 10,240,000
    const size_t szXT = (size_t)NB * NP * DD;        // 10,485,760
    unsigned short* Q   = ws16;
    unsigned short* K   = Q + szQ;
    unsigned short* V   = K + szQ;
    unsigned short* XT  = V + szQ;
    unsigned short* WT  = XT + szXT;                 // 768*256
    unsigned short* WoT = WT + (size_t)N3 * DD;      // 256*256
    unsigned short* AO  = WoT + (size_t)DD * DD;     // (b, 640, 256) bf16
    unsigned short* BT  = AO + szXT;                 // (8, 640, 640) bf16, (h,j,i)

    xT_kernel     <<<dim3(10, 4, NB), 256, 0, stream>>>(x, XT);
    transpose_cast<<<dim3(12, 4, 1),  256, 0, stream>>>(w_qkv, WT, DD, N3);
    transpose_cast<<<dim3(4, 4, 1),   256, 0, stream>>>(w_out, WoT, DD, DD);
    biasT_kernel  <<<dim3(10, 10, 1), 256, 0, stream>>>(rel, table, BT);
    qkv_mfma      <<<dim3(5, 6, NB),  256, 0, stream>>>(XT, WT, Q, K, V);
    attn_kernel   <<<dim3(10, NH, NB), 256, 0, stream>>>(Q, K, V, BT, AO);
    outproj_mfma  <<<dim3(5, 2, NB),  256, 0, stream>>>(AO, WoT, out);
}